// Round 12
// baseline (918.904 us; speedup 1.0000x reference)
//
#include <hip/hip_runtime.h>
#include <stdint.h>

typedef unsigned short u16;
typedef __attribute__((ext_vector_type(8))) short short8;
typedef __attribute__((ext_vector_type(4))) float f32x4;

#define NE   8
#define DIN  2048
#define DOUT 8192
#define NTOK 16384

__device__ __forceinline__ u16 f2bf(float f) {
  uint32_t u = __builtin_bit_cast(uint32_t, f);
  u += 0x7FFFu + ((u >> 16) & 1u);   // RNE (inputs are finite normals)
  return (u16)(u >> 16);
}

__global__ __launch_bounds__(256) void cvt_f32_bf16(const float* __restrict__ src,
                                                    u16* __restrict__ dst, size_t n) {
  size_t i = ((size_t)blockIdx.x * 256 + threadIdx.x) * 8;
  const size_t stride = (size_t)gridDim.x * 256 * 8;
  for (; i < n; i += stride) {
    f32x4 a = *(const f32x4*)(src + i);
    f32x4 b = *(const f32x4*)(src + i + 4);
    short8 o;
    o[0] = (short)f2bf(a[0]); o[1] = (short)f2bf(a[1]);
    o[2] = (short)f2bf(a[2]); o[3] = (short)f2bf(a[3]);
    o[4] = (short)f2bf(b[0]); o[5] = (short)f2bf(b[1]);
    o[6] = (short)f2bf(b[2]); o[7] = (short)f2bf(b[3]);
    *(short8*)(dst + i) = o;
  }
}

#define GLOAD_LDS16(g, l) __builtin_amdgcn_global_load_lds( \
    (const __attribute__((address_space(1))) void*)(g),     \
    (__attribute__((address_space(3))) void*)(l), 16, 0, 0)

// ---------------------------------------------------------------------------
// r12: FUSED W conversion, register-neutral (r9's failure mode avoided):
// W staged f32 DIRECTLY into LDS via global_load_lds (no reg round-trip);
// f32->bf16 happens during the fragment read (2x ds_read_b128 f32 + 8 cvts,
// transient temps only). The 150us cvt_w pre-pass is DELETED.
// Geometry: 256x256 tile, BK=32, 64 K-tiles, 2 phases each (r8's proven
// read/stage-pre-barrier pattern): ph1 {stage A+B(t+1) [6 gloads]; rd a03+b
// [12 reads]; BAR; MMQ(0)}; ph2 {rd a47; VMW(0); BAR; MMQ(4)}.
// VMW(0) drains 2-phase-old loads (landed) -> no counted-wait races at all.
// LDS 96KB: A bf16 [2][256][32] (32KB, r8 swizzle: phys=q^((r>>1)&3),
// measured 0 conflicts) + B f32 [2][256][32] (64KB, phys 16B-granule
// d = q ^ (r&7); read phys (2h+j)^(l&7): 8 lanes/16B-position = free).
// Epilogue: r11's LDS-repack coalesced nontemporal dwordx4 (fits in 96KB).
// ---------------------------------------------------------------------------
__global__ __launch_bounds__(512, 2) void moe_gemm8(
    const u16* __restrict__ Xb, const float* __restrict__ Wf,
    const int* __restrict__ counts, const float* __restrict__ bias,
    float* __restrict__ C) {
  extern __shared__ u16 sm[];          // 98304 B total
  float* smBf = (float*)(sm + 16384);  // B region: [2][8192] f32

  const int tid = threadIdx.x;
  const int l = tid & 63;
  const int wid = tid >> 6;      // 0..7
  const int wr = wid >> 2;       // 0..1  (M halves of 128)
  const int wc = wid & 3;        // 0..3  (N quarters of 64)

  // XCD-bijective swizzle: 2048 blocks, 256/XCD == tiles/expert => expert==XCD
  const int id = blockIdx.x;
  const int swz = (id & 7) * 256 + (id >> 3);
  const int e = swz >> 8;
  const int rem = swz & 255;
  const int tn = rem >> 3;       // 0..31 (8 consecutive blocks share W-panel)
  const int tm = rem & 7;        // 0..7

  int off = 0;
  for (int i = 0; i < e; ++i) off += counts[i];
  const int row0 = off + tm * 256;
  const int col0 = tn * 256;
  const size_t wbase = (size_t)e * DOUT * DIN + (size_t)col0 * DIN;

  // -- A staging (bf16, pre-swizzled source, linear gload_lds dest)
  const int rl = l >> 2;                     // row within 16-row slice
  const int qA = (l & 3) ^ ((l >> 3) & 3);   // logical granule (8 u16)
  const int s0 = wid * 2, s1 = s0 + 1;       // 2 slices of 16 rows
  const u16* pA0 = Xb + (size_t)(row0 + s0 * 16 + rl) * DIN + qA * 8;
  const u16* pA1 = Xb + (size_t)(row0 + s1 * 16 + rl) * DIN + qA * 8;

  // -- B staging (f32, pre-swizzled source, linear gload_lds dest)
  const int rj = l >> 3;                     // row within 8-row slice
  const int qB = (l & 7) ^ rj;               // logical granule (4 f32)
  const int sb = wid * 4;                    // 4 slices of 8 rows
  const float* pB0 = Wf + wbase + (size_t)((sb + 0) * 8 + rj) * DIN + qB * 4;
  const float* pB1 = Wf + wbase + (size_t)((sb + 1) * 8 + rj) * DIN + qB * 4;
  const float* pB2 = Wf + wbase + (size_t)((sb + 2) * 8 + rj) * DIN + qB * 4;
  const float* pB3 = Wf + wbase + (size_t)((sb + 3) * 8 + rj) * DIN + qB * 4;

  // -- A fragment read (r8-verified swizzle)
  const int gph = (l >> 4) ^ (((l & 15) >> 1) & 3);
  const int aoff = (wr * 128 + (l & 15)) * 32 + gph * 8;
  // -- B fragment read (f32, swizzled)
  const int h = l >> 4;
  const int bo0 = (wc * 64 + (l & 15)) * 32 + ((2 * h) ^ (l & 7)) * 4;
  const int bo1 = (wc * 64 + (l & 15)) * 32 + ((2 * h + 1) ^ (l & 7)) * 4;

  f32x4 acc[8][4] = {};
  short8 a[4], b[4];

#define SMA(buf) (sm + (buf) * 8192)
#define SMB(buf) (smBf + (buf) * 8192)
#define STAGE_A(buf, kt) do { const int ko = (kt) * 32;          \
    GLOAD_LDS16(pA0 + ko, SMA(buf) + s0 * 512);                  \
    GLOAD_LDS16(pA1 + ko, SMA(buf) + s1 * 512); } while (0)
#define STAGE_B(buf, kt) do { const int ko = (kt) * 32;          \
    GLOAD_LDS16(pB0 + ko, SMB(buf) + (sb + 0) * 256);            \
    GLOAD_LDS16(pB1 + ko, SMB(buf) + (sb + 1) * 256);            \
    GLOAD_LDS16(pB2 + ko, SMB(buf) + (sb + 2) * 256);            \
    GLOAD_LDS16(pB3 + ko, SMB(buf) + (sb + 3) * 256); } while (0)
#define RA4(buf, mb) do { _Pragma("unroll") for (int mf = 0; mf < 4; ++mf) \
    a[mf] = *(const short8*)(SMA(buf) + aoff + ((mb) + mf) * 512); } while (0)
#define RB4F(buf) do { _Pragma("unroll") for (int nf = 0; nf < 4; ++nf) {  \
    f32x4 v0 = *(const f32x4*)(SMB(buf) + bo0 + nf * 512);                 \
    f32x4 v1 = *(const f32x4*)(SMB(buf) + bo1 + nf * 512);                 \
    short8 t_;                                                             \
    _Pragma("unroll") for (int j = 0; j < 4; ++j) {                        \
      t_[j] = (short)f2bf(v0[j]); t_[4 + j] = (short)f2bf(v1[j]); }        \
    b[nf] = t_; } } while (0)
#define FENCE() asm volatile("" ::: "memory")
#define BAR() do { FENCE(); __builtin_amdgcn_s_barrier(); FENCE(); } while (0)
#define VMW(N) asm volatile("s_waitcnt vmcnt(" #N ")" ::: "memory")
#define LGKM0() asm volatile("s_waitcnt lgkmcnt(0)" ::: "memory")
#define MMQ(mb) do { __builtin_amdgcn_s_setprio(1);                                \
    _Pragma("unroll") for (int mf = 0; mf < 4; ++mf)                               \
      _Pragma("unroll") for (int nf = 0; nf < 4; ++nf)                             \
        acc[(mb) + mf][nf] =                                                       \
          __builtin_amdgcn_mfma_f32_16x16x32_bf16(a[mf], b[nf], acc[(mb) + mf][nf], 0, 0, 0); \
    __builtin_amdgcn_s_setprio(0); } while (0)

  const int NKT = DIN / 32;  // 64 K-tiles

  // prologue: tile 0 staged; full drain (cold, once).
  STAGE_A(0, 0); STAGE_B(0, 0);
  VMW(0);
  BAR();

  for (int kt = 0; kt < NKT; kt += 2) {
#define TILE(cur, nxt, t) do {                                          \
    const bool hn = (t) + 1 < NKT;                                      \
    /* ph1: stage next tile (6 gloads, issue-earliest); read a03 + b */ \
    if (hn) { STAGE_A(nxt, (t) + 1); STAGE_B(nxt, (t) + 1); }           \
    RA4(cur, 0); RB4F(cur);                                             \
    BAR(); MMQ(0);                                                      \
    /* ph2: read a47; publish next tile (loads ~2 phases old) */        \
    RA4(cur, 4);                                                        \
    VMW(0);                                                             \
    BAR(); MMQ(4); } while (0)
    TILE(0, 1, kt);
    TILE(1, 0, kt + 1);
#undef TILE
  }

  // ---- epilogue: LDS repack -> coalesced nontemporal dwordx4 stores ----
  BAR();  // all K-loop LDS reads complete; LDS is now free scratch
  float* smf = (float*)sm;
  const int cbw = col0 + wc * 64;             // wave's 64-col span
  const int r0 = (l >> 4) << 2;               // acc row offset within frag
  const f32x4 bv4 = *(const f32x4*)(bias + (size_t)e * DOUT + cbw + (l & 15) * 4);

#pragma unroll
  for (int m = 0; m < 8; ++m) {
    float* eb = smf + (wid * 2 + (m & 1)) * 1088;   // 16x68 f32, dbuf'd
#pragma unroll
    for (int n = 0; n < 4; ++n) {
      const int c = n * 16 + (l & 15);
#pragma unroll
      for (int j = 0; j < 4; ++j)
        eb[(r0 + j) * 68 + c] = acc[m][n][j];
    }
    LGKM0();  // own writes visible (wave-private region)
    const int rbm = row0 + wr * 128 + m * 16;
#pragma unroll
    for (int i = 0; i < 4; ++i) {
      const int row = i * 4 + (l >> 4);
      f32x4 v = *(const f32x4*)(eb + row * 68 + (l & 15) * 4);
      v = v + bv4;
      __builtin_nontemporal_store(
          v, (f32x4*)(C + (size_t)(rbm + row) * DOUT + cbw + (l & 15) * 4));
    }
  }
}

// ---------------------------------------------------------------------------
// Fallback (ws too small): fused fp32->bf16 staging, 128x128 m97 structure.
// ---------------------------------------------------------------------------
__global__ __launch_bounds__(256) void moe_gemm_fused(
    const float* __restrict__ Xf, const float* __restrict__ Wf,
    const int* __restrict__ counts, const float* __restrict__ bias,
    float* __restrict__ C) {
  __shared__ __align__(16) u16 lds[2][2][128 * 32];

  const int tid = threadIdx.x;
  const int lane = tid & 63;
  const int wid = tid >> 6;
  const int wr = wid >> 1;
  const int wc = wid & 1;

  const int id = blockIdx.x;
  const int swz = (id & 7) * ((int)gridDim.x >> 3) + (id >> 3);
  const int e = swz >> 10;
  const int rem = swz & 1023;
  const int tn = rem >> 4;
  const int tml = rem & 15;

  int off = 0;
  for (int i = 0; i < e; ++i) off += counts[i];
  const int row0 = off + tml * 128;
  const int col0 = tn * 128;
  const size_t wbase = (size_t)e * DOUT * DIN + (size_t)col0 * DIN;

  f32x4 acc[4][4] = {};

  auto stage = [&](int buf, int kt) {
#pragma unroll
    for (int s = 0; s < 2; ++s) {
      int i = s * 256 + tid;
      int r = i >> 2, c = i & 3;
      const float* sa = Xf + (size_t)(row0 + r) * DIN + kt * 32 + c * 8;
      const float* sb = Wf + wbase + (size_t)r * DIN + kt * 32 + c * 8;
      f32x4 a0 = *(const f32x4*)sa;
      f32x4 a1 = *(const f32x4*)(sa + 4);
      f32x4 b0 = *(const f32x4*)sb;
      f32x4 b1 = *(const f32x4*)(sb + 4);
      short8 va, vb;
#pragma unroll
      for (int j = 0; j < 4; ++j) {
        va[j] = (short)f2bf(a0[j]); va[j + 4] = (short)f2bf(a1[j]);
        vb[j] = (short)f2bf(b0[j]); vb[j + 4] = (short)f2bf(b1[j]);
      }
      *(short8*)&lds[buf][0][i * 8] = va;
      *(short8*)&lds[buf][1][i * 8] = vb;
    }
  };

  auto compute = [&](int buf) {
    const int kc = lane >> 4;
    const int rr = lane & 15;
    short8 a[4], b[4];
    const u16* lA = lds[buf][0];
    const u16* lB = lds[buf][1];
#pragma unroll
    for (int m = 0; m < 4; ++m)
      a[m] = *(const short8*)(lA + (wr * 64 + m * 16 + rr) * 32 + kc * 8);
#pragma unroll
    for (int n = 0; n < 4; ++n)
      b[n] = *(const short8*)(lB + (wc * 64 + n * 16 + rr) * 32 + kc * 8);
#pragma unroll
    for (int m = 0; m < 4; ++m)
#pragma unroll
      for (int n = 0; n < 4; ++n)
        acc[m][n] = __builtin_amdgcn_mfma_f32_16x16x32_bf16(a[m], b[n], acc[m][n], 0, 0, 0);
  };

  stage(0, 0);
  for (int kt = 0; kt < DIN / 32; ++kt) {
    __syncthreads();
    if (kt + 1 < DIN / 32) stage((kt + 1) & 1, kt + 1);
    compute(kt & 1);
  }

  const int rbase = row0 + wr * 64;
  const int cbase = col0 + wc * 64;
#pragma unroll
  for (int n = 0; n < 4; ++n) {
    const int col = cbase + n * 16 + (lane & 15);
    const float bv = bias[e * DOUT + col];
#pragma unroll
    for (int m = 0; m < 4; ++m) {
      const int r0 = rbase + m * 16 + (lane >> 4) * 4;
#pragma unroll
      for (int j = 0; j < 4; ++j)
        C[(size_t)(r0 + j) * DOUT + col] = acc[m][n][j] + bv;
    }
  }
}

extern "C" void kernel_launch(void* const* d_in, const int* in_sizes, int n_in,
                              void* d_out, int out_size, void* d_ws, size_t ws_size,
                              hipStream_t stream) {
  const float* inp = (const float*)d_in[0];
  const int* counts = (const int*)d_in[1];
  const float* weight = (const float*)d_in[2];
  const float* bias = (const float*)d_in[3];
  float* out = (float*)d_out;

  const size_t nx = (size_t)NTOK * DIN;
  const size_t need = nx * sizeof(u16);   // only X is pre-converted now

  if (ws_size >= need) {
    u16* xb = (u16*)d_ws;
    cvt_f32_bf16<<<2048, 256, 0, stream>>>(inp, xb, nx);
    const int grid = (NTOK / 256) * (DOUT / 256);  // 2048
    moe_gemm8<<<grid, 512, 98304, stream>>>(xb, weight, counts, bias, out);
  } else {
    const int grid = (NTOK / 128) * (DOUT / 128);  // 8192
    moe_gemm_fused<<<grid, 256, 0, stream>>>(inp, weight, counts, bias, out);
  }
}

// Round 13
// 776.645 us; speedup vs baseline: 1.1832x; 1.1832x over previous
//
#include <hip/hip_runtime.h>
#include <stdint.h>

typedef unsigned short u16;
typedef __attribute__((ext_vector_type(8))) short short8;
typedef __attribute__((ext_vector_type(4))) float f32x4;
typedef __attribute__((ext_vector_type(16))) float f32x16;

#define NE   8
#define DIN  2048
#define DOUT 8192
#define NTOK 16384

__device__ __forceinline__ u16 f2bf(float f) {
  uint32_t u = __builtin_bit_cast(uint32_t, f);
  u += 0x7FFFu + ((u >> 16) & 1u);   // RNE (inputs are finite normals)
  return (u16)(u >> 16);
}

__global__ __launch_bounds__(256) void cvt_f32_bf16(const float* __restrict__ src,
                                                    u16* __restrict__ dst, size_t n) {
  size_t i = ((size_t)blockIdx.x * 256 + threadIdx.x) * 8;
  const size_t stride = (size_t)gridDim.x * 256 * 8;
  for (; i < n; i += stride) {
    f32x4 a = *(const f32x4*)(src + i);
    f32x4 b = *(const f32x4*)(src + i + 4);
    short8 o;
    o[0] = (short)f2bf(a[0]); o[1] = (short)f2bf(a[1]);
    o[2] = (short)f2bf(a[2]); o[3] = (short)f2bf(a[3]);
    o[4] = (short)f2bf(b[0]); o[5] = (short)f2bf(b[1]);
    o[6] = (short)f2bf(b[2]); o[7] = (short)f2bf(b[3]);
    *(short8*)(dst + i) = o;
  }
}

#define GLOAD_LDS16(g, l) __builtin_amdgcn_global_load_lds( \
    (const __attribute__((address_space(1))) void*)(g),     \
    (__attribute__((address_space(3))) void*)(l), 16, 0, 0)

// ---------------------------------------------------------------------------
// r13 = r11 (verified best: 730us total; 4-barrier/K-tile schedule, 0-conflict
// staging swizzle, counted vmcnt, LDS-repack epilogue, cvt pre-passes) with
// ONE change: 16x16x32 -> 32x32x16 MFMA (same FLOP in half the issue slots,
// 2382 vs 2075 TF ubench ceiling). r12's fused-W REVERTED (conflicts + 8x
// redundant cvt). r5's earlier 32x32 regression bundled staging/vmcnt changes
// since shown (r7/r8) to explain it; this isolates the shape.
// Fragment mapping (m74/m101 verified): A/B row|col = l&31, k-granule
// logical = 2*kk + (l>>5); phys = logical ^ ((l>>1)&3) — same involution
// family as the measured-0 16x16 swizzle; staging unchanged.
// C/D: col = lane&31, row = (g&3) + 8*(g>>2) + 4*(lane>>5).
// ---------------------------------------------------------------------------
__global__ __launch_bounds__(512, 2) void moe_gemm8(
    const u16* __restrict__ Xb, const u16* __restrict__ Wb,
    const int* __restrict__ counts, const float* __restrict__ bias,
    float* __restrict__ C) {
  extern __shared__ u16 sm[];  // 65536 u16 = 128 KiB

  const int tid = threadIdx.x;
  const int l = tid & 63;
  const int wid = tid >> 6;      // 0..7
  const int wr = wid >> 2;       // 0..1  (M halves of 128)
  const int wc = wid & 3;        // 0..3  (N quarters of 64)

  // XCD-bijective swizzle: 2048 blocks, 256/XCD == tiles/expert => expert==XCD
  const int id = blockIdx.x;
  const int swz = (id & 7) * 256 + (id >> 3);
  const int e = swz >> 8;
  const int rem = swz & 255;
  const int tn = rem >> 3;       // 0..31 (8 consecutive blocks share B-panel)
  const int tm = rem & 7;        // 0..7

  int off = 0;
  for (int i = 0; i < e; ++i) off += counts[i];
  const int row0 = off + tm * 256;
  const int col0 = tn * 256;
  const size_t wbase = (size_t)e * DOUT * DIN + (size_t)col0 * DIN;

  // -- staging per-lane constants (pre-swizzled global source, linear dest)
  const int rl = l >> 2;                     // row within 16-row slice
  const int q = (l & 3) ^ ((l >> 3) & 3);    // source k-granule (inverse swz)
  const int s0 = wid * 2, s1 = s0 + 1;       // this wave's 2 slices of 16
  const u16* pA0 = Xb + (size_t)(row0 + s0 * 16 + rl) * DIN + q * 8;
  const u16* pA1 = Xb + (size_t)(row0 + s1 * 16 + rl) * DIN + q * 8;
  const u16* pB0 = Wb + wbase + (size_t)(s0 * 16 + rl) * DIN + q * 8;
  const u16* pB1 = Wb + wbase + (size_t)(s1 * 16 + rl) * DIN + q * 8;

  // -- fragment-read per-lane constants (32x32 layout, staged swizzle
  //    phys = logical ^ ((row>>1)&3); row = l&31 -> fsw = (l>>1)&3)
  const int fsw = (l >> 1) & 3;
  const int h = l >> 5;
  const int pk0 = (0 + h) ^ fsw;             // kk=0 phys granule
  const int pk1 = (2 + h) ^ fsw;             // kk=1 phys granule
  const int arow = (wr * 128 + (l & 31)) * 32;
  const int brow = (wc * 64 + (l & 31)) * 32;
  const int aoff0 = arow + pk0 * 8, aoff1 = arow + pk1 * 8;
  const int boff0 = brow + pk0 * 8, boff1 = brow + pk1 * 8;

  f32x16 acc[4][2] = {};
  short8 a[2][2], b[2][2];   // [pair-idx][kk], [nf][kk] — all statically indexed

#define SMA(buf, kh) (sm + (buf) * 32768 + (kh) * 8192)
#define SMB(buf, kh) (sm + (buf) * 32768 + 16384 + (kh) * 8192)
#define STAGE_A(buf, kt, kh) do { const int ko = (kt) * 64 + (kh) * 32; \
    GLOAD_LDS16(pA0 + ko, SMA(buf, kh) + s0 * 512);                     \
    GLOAD_LDS16(pA1 + ko, SMA(buf, kh) + s1 * 512); } while (0)
#define STAGE_B(buf, kt, kh) do { const int ko = (kt) * 64 + (kh) * 32; \
    GLOAD_LDS16(pB0 + ko, SMB(buf, kh) + s0 * 512);                     \
    GLOAD_LDS16(pB1 + ko, SMB(buf, kh) + s1 * 512); } while (0)
#define RA2(buf, kh, mb) do { _Pragma("unroll") for (int mp = 0; mp < 2; ++mp) { \
    a[mp][0] = *(const short8*)(SMA(buf, kh) + aoff0 + ((mb) + mp) * 1024);      \
    a[mp][1] = *(const short8*)(SMA(buf, kh) + aoff1 + ((mb) + mp) * 1024); } } while (0)
#define RB2(buf, kh) do { _Pragma("unroll") for (int nf = 0; nf < 2; ++nf) { \
    b[nf][0] = *(const short8*)(SMB(buf, kh) + boff0 + nf * 1024);           \
    b[nf][1] = *(const short8*)(SMB(buf, kh) + boff1 + nf * 1024); } } while (0)
#define FENCE() asm volatile("" ::: "memory")
#define BAR() do { FENCE(); __builtin_amdgcn_s_barrier(); FENCE(); } while (0)
#define VMW(N) asm volatile("s_waitcnt vmcnt(" #N ")" ::: "memory")
#define LGKM0() asm volatile("s_waitcnt lgkmcnt(0)" ::: "memory")
#define MMP(mb) do { __builtin_amdgcn_s_setprio(1);                            \
    _Pragma("unroll") for (int kk = 0; kk < 2; ++kk)                           \
      _Pragma("unroll") for (int mp = 0; mp < 2; ++mp)                         \
        _Pragma("unroll") for (int nf = 0; nf < 2; ++nf)                       \
          acc[(mb) + mp][nf] = __builtin_amdgcn_mfma_f32_32x32x16_bf16(        \
              a[mp][kk], b[nf][kk], acc[(mb) + mp][nf], 0, 0, 0);              \
    __builtin_amdgcn_s_setprio(0); } while (0)

  const int NKT = DIN / 64;  // 32 K-tiles

  // prologue: tile 0 staged (kh0 first); VMW(4) publishes kh0, kh1 in flight.
  STAGE_A(0, 0, 0); STAGE_B(0, 0, 0); STAGE_A(0, 0, 1); STAGE_B(0, 0, 1);
  VMW(4);
  BAR();

  for (int kt = 0; kt < NKT; kt += 2) {
#define TILE(cur, nxt, t) do {                                          \
    const bool hn = (t) + 1 < NKT;                                      \
    /* ph1: kh0 m-frags 0-1 (8 reads pre-bar) */                        \
    RA2(cur, 0, 0); RB2(cur, 0);                                        \
    if (hn) STAGE_A(nxt, (t) + 1, 0);                                   \
    BAR(); MMP(0);                                                      \
    /* ph2: kh0 m-frags 2-3 (4 reads) ; publish cur-kh1 */              \
    RA2(cur, 0, 2);                                                     \
    if (hn) { STAGE_B(nxt, (t) + 1, 0); VMW(4); } else VMW(0);          \
    BAR(); MMP(2);                                                      \
    /* ph3: kh1 m-frags 0-1 (8 reads) */                                \
    RA2(cur, 1, 0); RB2(cur, 1);                                        \
    if (hn) STAGE_A(nxt, (t) + 1, 1);                                   \
    BAR(); MMP(0);                                                      \
    /* ph4: kh1 m-frags 2-3 (4 reads) ; publish next-kh0 */             \
    RA2(cur, 1, 2);                                                     \
    if (hn) { STAGE_B(nxt, (t) + 1, 1); VMW(4); }                       \
    BAR(); MMP(2); } while (0)
    TILE(0, 1, kt);
    TILE(1, 0, kt + 1);
#undef TILE
  }

  // ---- epilogue: LDS repack -> coalesced nontemporal dwordx4 stores ----
  BAR();  // all K-loop LDS reads complete; LDS is now free scratch
  float* smf = (float*)sm;
  const int cbw = col0 + wc * 64;             // wave's 64-col span
  const f32x4 bv4 = *(const f32x4*)(bias + (size_t)e * DOUT + cbw + (l & 15) * 4);
  float* eb = smf + wid * 2176;               // 32x68 f32 per wave (8704 B)

#pragma unroll
  for (int mf = 0; mf < 4; ++mf) {
    if (mf) LGKM0();  // WAR: prior readback of eb complete before overwrite
    // scatter acc frag: col = l&31 (+nf*32), row = (g&3)+8*(g>>2)+4*h
#pragma unroll
    for (int nf = 0; nf < 2; ++nf)
#pragma unroll
      for (int g = 0; g < 16; ++g) {
        const int row = (g & 3) + 8 * (g >> 2) + 4 * h;
        eb[row * 68 + nf * 32 + (l & 31)] = acc[mf][nf][g];
      }
    LGKM0();  // own writes visible (wave-private region)
    const int rbm = row0 + wr * 128 + mf * 32;
#pragma unroll
    for (int i = 0; i < 8; ++i) {
      const int row = i * 4 + (l >> 4);
      f32x4 v = *(const f32x4*)(eb + row * 68 + (l & 15) * 4);
      v = v + bv4;
      __builtin_nontemporal_store(
          v, (f32x4*)(C + (size_t)(rbm + row) * DOUT + cbw + (l & 15) * 4));
    }
  }
}

// ---------------------------------------------------------------------------
// Fallback (ws too small): fused fp32->bf16 staging, 128x128 m97 structure.
// ---------------------------------------------------------------------------
__global__ __launch_bounds__(256) void moe_gemm_fused(
    const float* __restrict__ Xf, const float* __restrict__ Wf,
    const int* __restrict__ counts, const float* __restrict__ bias,
    float* __restrict__ C) {
  __shared__ __align__(16) u16 lds[2][2][128 * 32];

  const int tid = threadIdx.x;
  const int lane = tid & 63;
  const int wid = tid >> 6;
  const int wr = wid >> 1;
  const int wc = wid & 1;

  const int id = blockIdx.x;
  const int swz = (id & 7) * ((int)gridDim.x >> 3) + (id >> 3);
  const int e = swz >> 10;
  const int rem = swz & 1023;
  const int tn = rem >> 4;
  const int tml = rem & 15;

  int off = 0;
  for (int i = 0; i < e; ++i) off += counts[i];
  const int row0 = off + tml * 128;
  const int col0 = tn * 128;
  const size_t wbase = (size_t)e * DOUT * DIN + (size_t)col0 * DIN;

  f32x4 acc[4][4] = {};

  auto stage = [&](int buf, int kt) {
#pragma unroll
    for (int s = 0; s < 2; ++s) {
      int i = s * 256 + tid;
      int r = i >> 2, c = i & 3;
      const float* sa = Xf + (size_t)(row0 + r) * DIN + kt * 32 + c * 8;
      const float* sb = Wf + wbase + (size_t)r * DIN + kt * 32 + c * 8;
      f32x4 a0 = *(const f32x4*)sa;
      f32x4 a1 = *(const f32x4*)(sa + 4);
      f32x4 b0 = *(const f32x4*)sb;
      f32x4 b1 = *(const f32x4*)(sb + 4);
      short8 va, vb;
#pragma unroll
      for (int j = 0; j < 4; ++j) {
        va[j] = (short)f2bf(a0[j]); va[j + 4] = (short)f2bf(a1[j]);
        vb[j] = (short)f2bf(b0[j]); vb[j + 4] = (short)f2bf(b1[j]);
      }
      *(short8*)&lds[buf][0][i * 8] = va;
      *(short8*)&lds[buf][1][i * 8] = vb;
    }
  };

  auto compute = [&](int buf) {
    const int kc = lane >> 4;
    const int rr = lane & 15;
    short8 a[4], b[4];
    const u16* lA = lds[buf][0];
    const u16* lB = lds[buf][1];
#pragma unroll
    for (int m = 0; m < 4; ++m)
      a[m] = *(const short8*)(lA + (wr * 64 + m * 16 + rr) * 32 + kc * 8);
#pragma unroll
    for (int n = 0; n < 4; ++n)
      b[n] = *(const short8*)(lB + (wc * 64 + n * 16 + rr) * 32 + kc * 8);
#pragma unroll
    for (int m = 0; m < 4; ++m)
#pragma unroll
      for (int n = 0; n < 4; ++n)
        acc[m][n] = __builtin_amdgcn_mfma_f32_16x16x32_bf16(a[m], b[n], acc[m][n], 0, 0, 0);
  };

  stage(0, 0);
  for (int kt = 0; kt < DIN / 32; ++kt) {
    __syncthreads();
    if (kt + 1 < DIN / 32) stage((kt + 1) & 1, kt + 1);
    compute(kt & 1);
  }

  const int rbase = row0 + wr * 64;
  const int cbase = col0 + wc * 64;
#pragma unroll
  for (int n = 0; n < 4; ++n) {
    const int col = cbase + n * 16 + (lane & 15);
    const float bv = bias[e * DOUT + col];
#pragma unroll
    for (int m = 0; m < 4; ++m) {
      const int r0 = rbase + m * 16 + (lane >> 4) * 4;
#pragma unroll
      for (int j = 0; j < 4; ++j)
        C[(size_t)(r0 + j) * DOUT + col] = acc[m][n][j] + bv;
    }
  }
}

extern "C" void kernel_launch(void* const* d_in, const int* in_sizes, int n_in,
                              void* d_out, int out_size, void* d_ws, size_t ws_size,
                              hipStream_t stream) {
  const float* inp = (const float*)d_in[0];
  const int* counts = (const int*)d_in[1];
  const float* weight = (const float*)d_in[2];
  const float* bias = (const float*)d_in[3];
  float* out = (float*)d_out;

  const size_t nx = (size_t)NTOK * DIN;
  const size_t nw = (size_t)NE * DOUT * DIN;
  const size_t need = (nx + nw) * sizeof(u16);

  if (ws_size >= need) {
    u16* xb = (u16*)d_ws;
    u16* wb = xb + nx;
    cvt_f32_bf16<<<2048, 256, 0, stream>>>(inp, xb, nx);
    cvt_f32_bf16<<<4096, 256, 0, stream>>>(weight, wb, nw);
    const int grid = (NTOK / 256) * (DOUT / 256);  // 2048
    moe_gemm8<<<grid, 512, 131072, stream>>>(xb, wb, counts, bias, out);
  } else {
    const int grid = (NTOK / 128) * (DOUT / 128);  // 8192
    moe_gemm_fused<<<grid, 256, 0, stream>>>(inp, weight, counts, bias, out);
  }
}

// Round 14
// 726.733 us; speedup vs baseline: 1.2644x; 1.0687x over previous
//
#include <hip/hip_runtime.h>
#include <stdint.h>

typedef unsigned short u16;
typedef __attribute__((ext_vector_type(8))) short short8;
typedef __attribute__((ext_vector_type(4))) float f32x4;

#define NE   8
#define DIN  2048
#define DOUT 8192
#define NTOK 16384

__device__ __forceinline__ u16 f2bf(float f) {
  uint32_t u = __builtin_bit_cast(uint32_t, f);
  u += 0x7FFFu + ((u >> 16) & 1u);   // RNE (inputs are finite normals)
  return (u16)(u >> 16);
}

__global__ __launch_bounds__(256) void cvt_f32_bf16(const float* __restrict__ src,
                                                    u16* __restrict__ dst, size_t n) {
  size_t i = ((size_t)blockIdx.x * 256 + threadIdx.x) * 8;
  const size_t stride = (size_t)gridDim.x * 256 * 8;
  for (; i < n; i += stride) {
    f32x4 a = *(const f32x4*)(src + i);
    f32x4 b = *(const f32x4*)(src + i + 4);
    short8 o;
    o[0] = (short)f2bf(a[0]); o[1] = (short)f2bf(a[1]);
    o[2] = (short)f2bf(a[2]); o[3] = (short)f2bf(a[3]);
    o[4] = (short)f2bf(b[0]); o[5] = (short)f2bf(b[1]);
    o[6] = (short)f2bf(b[2]); o[7] = (short)f2bf(b[3]);
    *(short8*)(dst + i) = o;
  }
}

#define GLOAD_LDS16(g, l) __builtin_amdgcn_global_load_lds( \
    (const __attribute__((address_space(1))) void*)(g),     \
    (__attribute__((address_space(3))) void*)(l), 16, 0, 0)

// ---------------------------------------------------------------------------
// r14 = r11 (verified best: 730us; 16x16x32, 0-conflict staging swizzle,
// coalesced epilogue) with the wait structure re-aligned to the m201
// template's single-wait-per-K-tile (T4):
//  - stage stream FIFO-aligned with read order:
//      p1: stage t+1:A.kh1  (nxt buf)    p3: stage t+2:A.kh0  (cur buf!)
//      p2: stage t+1:B.kh1  (nxt buf)    p4: stage t+2:B.kh0  (cur buf!)
//  - ONE VMW(4) per K-tile at p4 (queue=12 loads, drains 8 = ALL of t+1).
//  - LGKM0 BEFORE each barrier: when any wave passes BAR(p), all waves'
//    phase-p ds_reads are serviced => a same-buffer DMA issued in p+1 is
//    provably safe (cur.A.kh0 last read p2, overwritten p3; cur.B.kh0 read
//    p1, overwritten p4; kh1 slots read p3/p4, overwritten next tile p1/p2).
//    Bonus: MFMA clusters need no post-barrier lgkm wait.
//  - prologue: t0 all + t1:{A0,B0} (12 loads), VMW(4) drains t0 exactly.
//  - tail (r2 lesson: counted wait that would no-op races): t+2>=NKT ->
//    VMW(0) publishes t+1 (loads 2-4 phases old); t=NKT-1 -> no wait.
// 32x32 MFMA permanently abandoned (r5+r13: intrinsic 8-way read conflict).
// ---------------------------------------------------------------------------
__global__ __launch_bounds__(512, 2) void moe_gemm8(
    const u16* __restrict__ Xb, const u16* __restrict__ Wb,
    const int* __restrict__ counts, const float* __restrict__ bias,
    float* __restrict__ C) {
  extern __shared__ u16 sm[];  // 65536 u16 = 128 KiB

  const int tid = threadIdx.x;
  const int l = tid & 63;
  const int wid = tid >> 6;      // 0..7
  const int wr = wid >> 2;       // 0..1  (M halves of 128)
  const int wc = wid & 3;        // 0..3  (N quarters of 64)

  // XCD-bijective swizzle: 2048 blocks, 256/XCD == tiles/expert => expert==XCD
  const int id = blockIdx.x;
  const int swz = (id & 7) * 256 + (id >> 3);
  const int e = swz >> 8;
  const int rem = swz & 255;
  const int tn = rem >> 3;       // 0..31 (8 consecutive blocks share B-panel)
  const int tm = rem & 7;        // 0..7

  int off = 0;
  for (int i = 0; i < e; ++i) off += counts[i];
  const int row0 = off + tm * 256;
  const int col0 = tn * 256;
  const size_t wbase = (size_t)e * DOUT * DIN + (size_t)col0 * DIN;

  // -- staging per-lane constants (pre-swizzled global source, linear dest)
  const int rl = l >> 2;                     // row within 16-row slice
  const int q = (l & 3) ^ ((l >> 3) & 3);    // source k-granule (inverse swz)
  const int s0 = wid * 2, s1 = s0 + 1;       // this wave's 2 slices of 16
  const u16* pA0 = Xb + (size_t)(row0 + s0 * 16 + rl) * DIN + q * 8;
  const u16* pA1 = Xb + (size_t)(row0 + s1 * 16 + rl) * DIN + q * 8;
  const u16* pB0 = Wb + wbase + (size_t)(s0 * 16 + rl) * DIN + q * 8;
  const u16* pB1 = Wb + wbase + (size_t)(s1 * 16 + rl) * DIN + q * 8;

  // -- fragment-read per-lane constants (16x16 layout, r3-verified swizzle)
  const int f0 = ((l & 15) >> 1) & 3;
  const int gph = (l >> 4) ^ f0;             // physical granule 0..3
  const int aoff = (wr * 128 + (l & 15)) * 32 + gph * 8;
  const int boff = (wc * 64 + (l & 15)) * 32 + gph * 8;

  f32x4 acc[8][4] = {};
  short8 a[4], b[4];

#define SMA(buf, kh) (sm + (buf) * 32768 + (kh) * 8192)
#define SMB(buf, kh) (sm + (buf) * 32768 + 16384 + (kh) * 8192)
#define STAGE_A(buf, kt, kh) do { const int ko = (kt) * 64 + (kh) * 32; \
    GLOAD_LDS16(pA0 + ko, SMA(buf, kh) + s0 * 512);                     \
    GLOAD_LDS16(pA1 + ko, SMA(buf, kh) + s1 * 512); } while (0)
#define STAGE_B(buf, kt, kh) do { const int ko = (kt) * 64 + (kh) * 32; \
    GLOAD_LDS16(pB0 + ko, SMB(buf, kh) + s0 * 512);                     \
    GLOAD_LDS16(pB1 + ko, SMB(buf, kh) + s1 * 512); } while (0)
#define RA4(buf, kh, mb) do { _Pragma("unroll") for (int mf = 0; mf < 4; ++mf) \
    a[mf] = *(const short8*)(SMA(buf, kh) + aoff + ((mb) + mf) * 512); } while (0)
#define RB4(buf, kh) do { _Pragma("unroll") for (int nf = 0; nf < 4; ++nf) \
    b[nf] = *(const short8*)(SMB(buf, kh) + boff + nf * 512); } while (0)
#define FENCE() asm volatile("" ::: "memory")
#define BAR() do { FENCE(); __builtin_amdgcn_s_barrier(); FENCE(); } while (0)
#define VMW(N) asm volatile("s_waitcnt vmcnt(" #N ")" ::: "memory")
#define LGKM0() asm volatile("s_waitcnt lgkmcnt(0)" ::: "memory")
#define MMQ(mb) do { __builtin_amdgcn_s_setprio(1);                                \
    _Pragma("unroll") for (int mf = 0; mf < 4; ++mf)                               \
      _Pragma("unroll") for (int nf = 0; nf < 4; ++nf)                             \
        acc[(mb) + mf][nf] =                                                       \
          __builtin_amdgcn_mfma_f32_16x16x32_bf16(a[mf], b[nf], acc[(mb) + mf][nf], 0, 0, 0); \
    __builtin_amdgcn_s_setprio(0); } while (0)

  const int NKT = DIN / 64;  // 32 K-tiles

  // prologue: t0 fully + t1:{A0,B0} (12 loads); VMW(4) drains t0 exactly.
  STAGE_A(0, 0, 0); STAGE_B(0, 0, 0); STAGE_A(0, 0, 1); STAGE_B(0, 0, 1);
  STAGE_A(1, 1, 0); STAGE_B(1, 1, 0);
  VMW(4);
  BAR();

  for (int kt = 0; kt < NKT; kt += 2) {
#define TILE(cur, nxt, t) do {                                          \
    const bool h1 = (t) + 1 < NKT;   /* stage t+1 kh1 (nxt buf) */      \
    const bool h2 = (t) + 2 < NKT;   /* stage t+2 kh0 (cur buf) */      \
    /* p1: reads cur.A.kh0(m0-3) + cur.B.kh0 */                         \
    RA4(cur, 0, 0); RB4(cur, 0);                                        \
    if (h1) STAGE_A(nxt, (t) + 1, 1);                                   \
    LGKM0(); BAR(); MMQ(0);                                             \
    /* p2: reads cur.A.kh0(m4-7) */                                     \
    RA4(cur, 0, 4);                                                     \
    if (h1) STAGE_B(nxt, (t) + 1, 1);                                   \
    LGKM0(); BAR(); MMQ(4);                                             \
    /* p3: reads cur.A.kh1(m0-3) + cur.B.kh1 ; overwrite cur.A.kh0 */   \
    RA4(cur, 1, 0); RB4(cur, 1);                                        \
    if (h2) STAGE_A(cur, (t) + 2, 0);                                   \
    LGKM0(); BAR(); MMQ(0);                                             \
    /* p4: reads cur.A.kh1(m4-7) ; overwrite cur.B.kh0 ; publish t+1 */ \
    RA4(cur, 1, 4);                                                     \
    if (h2) { STAGE_B(cur, (t) + 2, 0); VMW(4); }                       \
    else if (h1) VMW(0);                                                \
    LGKM0(); BAR(); MMQ(4); } while (0)
    TILE(0, 1, kt);
    TILE(1, 0, kt + 1);
#undef TILE
  }

  // ---- epilogue: LDS repack -> coalesced nontemporal dwordx4 stores ----
  BAR();  // all K-loop LDS reads complete; LDS is now free scratch
  float* smf = (float*)sm;
  const int cbw = col0 + wc * 64;             // wave's 64-col span
  const int r0 = (l >> 4) << 2;               // acc row offset within frag
  const f32x4 bv4 = *(const f32x4*)(bias + (size_t)e * DOUT + cbw + (l & 15) * 4);

#pragma unroll
  for (int m = 0; m < 8; ++m) {
    float* eb = smf + (wid * 2 + (m & 1)) * 1088;   // 16x68 f32, dbuf'd
#pragma unroll
    for (int n = 0; n < 4; ++n) {
      const int c = n * 16 + (l & 15);
#pragma unroll
      for (int j = 0; j < 4; ++j)
        eb[(r0 + j) * 68 + c] = acc[m][n][j];
    }
    LGKM0();  // own writes visible (wave-private region)
    const int rbm = row0 + wr * 128 + m * 16;
#pragma unroll
    for (int i = 0; i < 4; ++i) {
      const int row = i * 4 + (l >> 4);
      f32x4 v = *(const f32x4*)(eb + row * 68 + (l & 15) * 4);
      v = v + bv4;
      __builtin_nontemporal_store(
          v, (f32x4*)(C + (size_t)(rbm + row) * DOUT + cbw + (l & 15) * 4));
    }
  }
}

// ---------------------------------------------------------------------------
// Fallback (ws too small): fused fp32->bf16 staging, 128x128 m97 structure.
// ---------------------------------------------------------------------------
__global__ __launch_bounds__(256) void moe_gemm_fused(
    const float* __restrict__ Xf, const float* __restrict__ Wf,
    const int* __restrict__ counts, const float* __restrict__ bias,
    float* __restrict__ C) {
  __shared__ __align__(16) u16 lds[2][2][128 * 32];

  const int tid = threadIdx.x;
  const int lane = tid & 63;
  const int wid = tid >> 6;
  const int wr = wid >> 1;
  const int wc = wid & 1;

  const int id = blockIdx.x;
  const int swz = (id & 7) * ((int)gridDim.x >> 3) + (id >> 3);
  const int e = swz >> 10;
  const int rem = swz & 1023;
  const int tn = rem >> 4;
  const int tml = rem & 15;

  int off = 0;
  for (int i = 0; i < e; ++i) off += counts[i];
  const int row0 = off + tml * 128;
  const int col0 = tn * 128;
  const size_t wbase = (size_t)e * DOUT * DIN + (size_t)col0 * DIN;

  f32x4 acc[4][4] = {};

  auto stage = [&](int buf, int kt) {
#pragma unroll
    for (int s = 0; s < 2; ++s) {
      int i = s * 256 + tid;
      int r = i >> 2, c = i & 3;
      const float* sa = Xf + (size_t)(row0 + r) * DIN + kt * 32 + c * 8;
      const float* sb = Wf + wbase + (size_t)r * DIN + kt * 32 + c * 8;
      f32x4 a0 = *(const f32x4*)sa;
      f32x4 a1 = *(const f32x4*)(sa + 4);
      f32x4 b0 = *(const f32x4*)sb;
      f32x4 b1 = *(const f32x4*)(sb + 4);
      short8 va, vb;
#pragma unroll
      for (int j = 0; j < 4; ++j) {
        va[j] = (short)f2bf(a0[j]); va[j + 4] = (short)f2bf(a1[j]);
        vb[j] = (short)f2bf(b0[j]); vb[j + 4] = (short)f2bf(b1[j]);
      }
      *(short8*)&lds[buf][0][i * 8] = va;
      *(short8*)&lds[buf][1][i * 8] = vb;
    }
  };

  auto compute = [&](int buf) {
    const int kc = lane >> 4;
    const int rr = lane & 15;
    short8 a[4], b[4];
    const u16* lA = lds[buf][0];
    const u16* lB = lds[buf][1];
#pragma unroll
    for (int m = 0; m < 4; ++m)
      a[m] = *(const short8*)(lA + (wr * 64 + m * 16 + rr) * 32 + kc * 8);
#pragma unroll
    for (int n = 0; n < 4; ++n)
      b[n] = *(const short8*)(lB + (wc * 64 + n * 16 + rr) * 32 + kc * 8);
#pragma unroll
    for (int m = 0; m < 4; ++m)
#pragma unroll
      for (int n = 0; n < 4; ++n)
        acc[m][n] = __builtin_amdgcn_mfma_f32_16x16x32_bf16(a[m], b[n], acc[m][n], 0, 0, 0);
  };

  stage(0, 0);
  for (int kt = 0; kt < DIN / 32; ++kt) {
    __syncthreads();
    if (kt + 1 < DIN / 32) stage((kt + 1) & 1, kt + 1);
    compute(kt & 1);
  }

  const int rbase = row0 + wr * 64;
  const int cbase = col0 + wc * 64;
#pragma unroll
  for (int n = 0; n < 4; ++n) {
    const int col = cbase + n * 16 + (lane & 15);
    const float bv = bias[e * DOUT + col];
#pragma unroll
    for (int m = 0; m < 4; ++m) {
      const int r0 = rbase + m * 16 + (lane >> 4) * 4;
#pragma unroll
      for (int j = 0; j < 4; ++j)
        C[(size_t)(r0 + j) * DOUT + col] = acc[m][n][j] + bv;
    }
  }
}

extern "C" void kernel_launch(void* const* d_in, const int* in_sizes, int n_in,
                              void* d_out, int out_size, void* d_ws, size_t ws_size,
                              hipStream_t stream) {
  const float* inp = (const float*)d_in[0];
  const int* counts = (const int*)d_in[1];
  const float* weight = (const float*)d_in[2];
  const float* bias = (const float*)d_in[3];
  float* out = (float*)d_out;

  const size_t nx = (size_t)NTOK * DIN;
  const size_t nw = (size_t)NE * DOUT * DIN;
  const size_t need = (nx + nw) * sizeof(u16);

  if (ws_size >= need) {
    u16* xb = (u16*)d_ws;
    u16* wb = xb + nx;
    cvt_f32_bf16<<<2048, 256, 0, stream>>>(inp, xb, nx);
    cvt_f32_bf16<<<4096, 256, 0, stream>>>(weight, wb, nw);
    const int grid = (NTOK / 256) * (DOUT / 256);  // 2048
    moe_gemm8<<<grid, 512, 131072, stream>>>(xb, wb, counts, bias, out);
  } else {
    const int grid = (NTOK / 128) * (DOUT / 128);  // 8192
    moe_gemm_fused<<<grid, 256, 0, stream>>>(inp, weight, counts, bias, out);
  }
}